// Round 2
// baseline (562.344 us; speedup 1.0000x reference)
//
#include <hip/hip_runtime.h>

// DynamicGraphAttention: B=16, L=256, D=128, F_IN=64, F_OUT=64
// v6 = v5 with the 8 in-loop barriers removed (phase-C P-tile, sEi, sL are
// wave-private: wave w builds and consumes rows [32w,32w+32) only), j-tile
// loop fully unrolled, and launch_bounds raised to 6 waves/EU (LDS already
// permits 6 blocks/CU at 27.1 KB). 3 barriers total instead of 11.
constexpr int D_   = 128;
constexpr int FIN  = 64;
constexpr int FOUT = 64;
constexpr float ALPHA = 0.2f;

typedef _Float16 f16x8 __attribute__((ext_vector_type(8)));
typedef float    f32x4 __attribute__((ext_vector_type(4)));

__global__ __launch_bounds__(256, 6) void gat_kernel(
    const float* __restrict__ hg, const int* __restrict__ adjg,
    const float* __restrict__ Wg, const float* __restrict__ ag,
    float* __restrict__ outg)
{
    // sX (16KB): phase A = h f16 [d][64] swz((d&7)<<4); phase B/C = WhT f16 [o][128] swz((o&7)<<4)
    __shared__ __align__(16) unsigned short sX[128 * 64];
    // sPt (8KB): phase A = W^T f16 [o][64] swz((o&7)<<4); phase C = P-tile f16 [i][32] swz((i&3)<<4)
    __shared__ __align__(16) unsigned short sPt[64 * 64];
    __shared__ __align__(16) float sA[2 * FOUT];
    __shared__ float sEi[D_];
    __shared__ __align__(16) float sEj[D_];
    __shared__ float sL[D_];
    __shared__ float sMxW[4];
    // total ~26.7 KB -> 6 blocks/CU by LDS

    const int tid  = threadIdx.x;
    const int lane = tid & 63;
    const int w    = tid >> 6;      // wave 0..3, owns output rows [w*32, w*32+32)
    const int g    = lane >> 4;     // k-group 0..3
    const int m16  = lane & 15;

    const long bl = blockIdx.x;
    const float* hp   = hg   + bl * (long)(D_ * FIN);
    const int*   adjp = adjg + bl * (long)(D_ * D_);
    float*       outp = outg + bl * (long)(D_ * FOUT);

    char* xb = (char*)sX;
    char* pb = (char*)sPt;

    const int pi  = tid >> 1;           // P-build row (wave-private: pi in [32w, 32w+32))
    const int pjb = (tid & 1) << 4;     // 16-j segment within 32-wide tile

    // ---------------- stage: h -> sX f16 swz, W -> sPt transposed f16 swz, a -> sA ----------------
    {
        const float4* h4 = (const float4*)hp;
        #pragma unroll
        for (int k = 0; k < 8; ++k) {
            int idx = tid + 256 * k;          // float4 index in [0,2048)
            float4 v = h4[idx];
            int row = idx >> 4;               // 16 float4 per 64-float row
            int f   = (idx & 15) << 2;
            union { _Float16 h[4]; uint2 u; } cv;
            cv.h[0] = (_Float16)v.x; cv.h[1] = (_Float16)v.y;
            cv.h[2] = (_Float16)v.z; cv.h[3] = (_Float16)v.w;
            int off = (row * 128 + f * 2) ^ ((row & 7) << 4);
            *(uint2*)(xb + off) = cv.u;
        }
        const float4* W4 = (const float4*)Wg;
        #pragma unroll
        for (int k = 0; k < 4; ++k) {
            int idx = tid + 256 * k;          // [0,1024)
            float4 v = W4[idx];
            int f  = idx >> 4;                // W row (F_IN)
            int o0 = (idx & 15) << 2;         // W col (F_OUT)
            float vv[4] = {v.x, v.y, v.z, v.w};
            #pragma unroll
            for (int q = 0; q < 4; ++q) {
                int o = o0 + q;
                int off = (o * 128 + f * 2) ^ ((o & 7) << 4);
                *(_Float16*)(pb + off) = (_Float16)vv[q];
            }
        }
        if (tid < 2 * FOUT) sA[tid] = ag[tid];
    }

    // prefetch adj tile 0 early (latency hides under staging + phase A/B)
    int4 areg[4];
    {
        const int4* ap = (const int4*)(adjp + pi * D_ + pjb);
        #pragma unroll
        for (int q = 0; q < 4; ++q) areg[q] = ap[q];
    }
    __syncthreads();   // B1: staged h/W visible to all waves

    // ---------------- phase A: Wh = h @ W via MFMA 16x16x32 f16 ----------------
    f32x4 acc[2][4];
    #pragma unroll
    for (int mt = 0; mt < 2; ++mt)
        #pragma unroll
        for (int nt = 0; nt < 4; ++nt) acc[mt][nt] = (f32x4){0.f, 0.f, 0.f, 0.f};

    #pragma unroll
    for (int kt = 0; kt < 2; ++kt) {
        f16x8 af[2], bf[4];
        #pragma unroll
        for (int mt = 0; mt < 2; ++mt) {
            int row = w * 32 + mt * 16 + m16;
            af[mt] = *(const f16x8*)(xb + ((row * 128 + kt * 64 + g * 16) ^ ((row & 7) << 4)));
        }
        #pragma unroll
        for (int nt = 0; nt < 4; ++nt) {
            int o = nt * 16 + m16;
            bf[nt] = *(const f16x8*)(pb + ((o * 128 + kt * 64 + g * 16) ^ ((o & 7) << 4)));
        }
        #pragma unroll
        for (int mt = 0; mt < 2; ++mt)
            #pragma unroll
            for (int nt = 0; nt < 4; ++nt)
                acc[mt][nt] = __builtin_amdgcn_mfma_f32_16x16x32_f16(af[mt], bf[nt], acc[mt][nt], 0, 0, 0);
    }
    __syncthreads();   // B2: all cross-wave sX/sPt reads done before WhT overwrites sX

    // ---------------- phase B: e_i/e_j via register butterfly; WhT -> sX ----------------
    {
        float a1v[4], a2v[4];
        #pragma unroll
        for (int nt = 0; nt < 4; ++nt) {
            a1v[nt] = sA[nt * 16 + m16];
            a2v[nt] = sA[FOUT + nt * 16 + m16];
        }
        float wmax = -3.0e38f;
        #pragma unroll
        for (int mt = 0; mt < 2; ++mt) {
            #pragma unroll
            for (int r = 0; r < 4; ++r) {
                float ei = 0.f, ej = 0.f;
                #pragma unroll
                for (int nt = 0; nt < 4; ++nt) {
                    float v = acc[mt][nt][r];
                    ei += v * a1v[nt];
                    ej += v * a2v[nt];
                }
                #pragma unroll
                for (int s = 1; s < 16; s <<= 1) {
                    ei += __shfl_xor(ei, s);
                    ej += __shfl_xor(ej, s);
                }
                int row = w * 32 + mt * 16 + g * 4 + r;   // D-frag row (col=lane&15, row=(lane>>4)*4+reg)
                if (m16 == 0) { sEi[row] = ei; sEj[row] = ej; }
                wmax = fmaxf(wmax, ej);
            }
        }
        wmax = fmaxf(wmax, __shfl_xor(wmax, 16));
        wmax = fmaxf(wmax, __shfl_xor(wmax, 32));
        if (lane == 0) sMxW[w] = wmax;

        // write Wh^T f16 into sX: WhT[o][j], 4 consecutive j per (mt,nt) = one 8B write
        #pragma unroll
        for (int mt = 0; mt < 2; ++mt) {
            int j0r = w * 32 + mt * 16 + g * 4;
            #pragma unroll
            for (int nt = 0; nt < 4; ++nt) {
                int o = nt * 16 + m16;
                union { _Float16 h[4]; uint2 u; } cv;
                cv.h[0] = (_Float16)acc[mt][nt][0];
                cv.h[1] = (_Float16)acc[mt][nt][1];
                cv.h[2] = (_Float16)acc[mt][nt][2];
                cv.h[3] = (_Float16)acc[mt][nt][3];
                int off = (o * 256 + j0r * 2) ^ ((o & 7) << 4);
                *(uint2*)(xb + off) = cv.u;
            }
        }
    }
    __syncthreads();   // B3: sEj / sMxW / WhT visible to all waves. Last block barrier.

    // ---------------- phase C: P build (f16, max-shifted) + P @ Wh via MFMA ----------------
    // NO barriers in this loop: P-tile rows, sEi, sL are wave-private; sEj/WhT are
    // read-only after B3. Same-wave LDS write->read is ordered by the DS pipe.
    #pragma unroll
    for (int mt = 0; mt < 2; ++mt)
        #pragma unroll
        for (int nt = 0; nt < 4; ++nt) acc[mt][nt] = (f32x4){0.f, 0.f, 0.f, 0.f};

    const float ei_pi = sEi[pi];
    const float mxj = fmaxf(fmaxf(sMxW[0], sMxW[1]), fmaxf(sMxW[2], sMxW[3]));
    float mt_ = ei_pi + mxj;
    const float mi = mt_ > 0.f ? mt_ : ALPHA * mt_;   // = max_j leaky(ei+ej) >= any row entry
    float lpt = 0.f;

    #pragma unroll
    for (int jt = 0; jt < 4; ++jt) {
        const int j0 = jt * 32;
        // build this thread's 16 p values (row pi, j = j0+pjb .. +16)
        union { _Float16 h[8]; uint4 u; } ph0, ph1;
        #pragma unroll
        for (int q = 0; q < 4; ++q) {
            int4 av = areg[q];
            int aa[4] = {av.x, av.y, av.z, av.w};
            float4 ej4 = *(const float4*)&sEj[j0 + pjb + q * 4];
            float ejv[4] = {ej4.x, ej4.y, ej4.z, ej4.w};
            #pragma unroll
            for (int kk = 0; kk < 4; ++kk) {
                float e = ei_pi + ejv[kk];
                e = e > 0.f ? e : ALPHA * e;
                float p = (aa[kk] > 0) ? __expf(e - mi) : 0.f;   // in (0,1] -> exact f16 range
                lpt += p;
                _Float16 pv = (_Float16)p;
                if (q < 2) ph0.h[q * 4 + kk] = pv;
                else       ph1.h[(q - 2) * 4 + kk] = pv;
            }
        }
        {
            int base = pi * 64 + pjb * 2;
            *(uint4*)(pb + ((base)      ^ ((pi & 3) << 4))) = ph0.u;
            *(uint4*)(pb + ((base + 16) ^ ((pi & 3) << 4))) = ph1.u;
        }
        if (jt < 3) {
            // prefetch next adj tile (overlaps with this tile's MFMA, no barrier in between)
            const int4* ap = (const int4*)(adjp + pi * D_ + (jt + 1) * 32 + pjb);
            #pragma unroll
            for (int q = 0; q < 4; ++q) areg[q] = ap[q];
        }

        // MFMA: acc += P[:, j0:j0+32] @ Wh[j0:j0+32, :]  (P rows are this wave's own)
        f16x8 pa[2], wb[4];
        #pragma unroll
        for (int mtx = 0; mtx < 2; ++mtx) {
            int i = w * 32 + mtx * 16 + m16;
            pa[mtx] = *(const f16x8*)(pb + ((i * 64 + g * 16) ^ ((i & 3) << 4)));
        }
        #pragma unroll
        for (int nt = 0; nt < 4; ++nt) {
            int o = nt * 16 + m16;
            wb[nt] = *(const f16x8*)(xb + ((o * 256 + j0 * 2 + g * 16) ^ ((o & 7) << 4)));
        }
        #pragma unroll
        for (int mtx = 0; mtx < 2; ++mtx)
            #pragma unroll
            for (int nt = 0; nt < 4; ++nt)
                acc[mtx][nt] = __builtin_amdgcn_mfma_f32_16x16x32_f16(pa[mtx], wb[nt], acc[mtx][nt], 0, 0, 0);
    }

    // row sums -> sL (wave-private, same-wave read below)
    lpt += __shfl_xor(lpt, 1);
    if ((tid & 1) == 0) sL[pi] = lpt;

    // ---------------- epilogue: divide by row sum, write out ----------------
    #pragma unroll
    for (int mtx = 0; mtx < 2; ++mtx) {
        #pragma unroll
        for (int r = 0; r < 4; ++r) {
            int row = w * 32 + mtx * 16 + g * 4 + r;
            float inv = 1.0f / sL[row];
            #pragma unroll
            for (int nt = 0; nt < 4; ++nt)
                outp[row * 64 + nt * 16 + m16] = acc[mtx][nt][r] * inv;
        }
    }
}

extern "C" void kernel_launch(void* const* d_in, const int* in_sizes, int n_in,
                              void* d_out, int out_size, void* d_ws, size_t ws_size,
                              hipStream_t stream) {
    const float* h   = (const float*)d_in[0];
    const int*   adj = (const int*)d_in[1];
    const float* W   = (const float*)d_in[2];
    const float* a   = (const float*)d_in[3];
    float*       out = (float*)d_out;
    gat_kernel<<<dim3(16 * 256), dim3(256), 0, stream>>>(h, adj, W, a, out);
}

// Round 3
// 475.407 us; speedup vs baseline: 1.1829x; 1.1829x over previous
//
#include <hip/hip_runtime.h>

// DynamicGraphAttention: B=16, L=256, D=128, F_IN=64, F_OUT=64
// v7 = v6 with launch_bounds reverted to (256,4): v6's (256,6) squeezed VGPRs
// 64->40 and spilled (~335MB extra HBM traffic). Keeps the 3-barrier structure
// (phase-C is wave-private). W staging reworked to per-thread 4x4 register
// transpose -> conflict-free 8B LDS writes (was ~8-way conflicted 2B writes).
constexpr int D_   = 128;
constexpr int FIN  = 64;
constexpr int FOUT = 64;
constexpr float ALPHA = 0.2f;

typedef _Float16 f16x8 __attribute__((ext_vector_type(8)));
typedef float    f32x4 __attribute__((ext_vector_type(4)));

__global__ __launch_bounds__(256, 4) void gat_kernel(
    const float* __restrict__ hg, const int* __restrict__ adjg,
    const float* __restrict__ Wg, const float* __restrict__ ag,
    float* __restrict__ outg)
{
    // sX (16KB): phase A = h f16 [d][64] swz((d&7)<<4); phase B/C = WhT f16 [o][128] swz((o&7)<<4)
    __shared__ __align__(16) unsigned short sX[128 * 64];
    // sPt (8KB): phase A = W^T f16 [o][64] swz((o&7)<<4); phase C = P-tile f16 [i][32] swz((i&3)<<4)
    __shared__ __align__(16) unsigned short sPt[64 * 64];
    __shared__ __align__(16) float sA[2 * FOUT];
    __shared__ float sEi[D_];
    __shared__ __align__(16) float sEj[D_];
    __shared__ float sL[D_];
    __shared__ float sMxW[4];

    const int tid  = threadIdx.x;
    const int lane = tid & 63;
    const int w    = tid >> 6;      // wave 0..3, owns output rows [w*32, w*32+32)
    const int g    = lane >> 4;     // k-group 0..3
    const int m16  = lane & 15;

    const long bl = blockIdx.x;
    const float* hp   = hg   + bl * (long)(D_ * FIN);
    const int*   adjp = adjg + bl * (long)(D_ * D_);
    float*       outp = outg + bl * (long)(D_ * FOUT);

    char* xb = (char*)sX;
    char* pb = (char*)sPt;

    const int pi  = tid >> 1;           // P-build row (wave-private: pi in [32w, 32w+32))
    const int pjb = (tid & 1) << 4;     // 16-j segment within 32-wide tile

    // ---------------- stage: h -> sX f16 swz, W -> sPt transposed f16 swz, a -> sA ----------------
    {
        const float4* h4 = (const float4*)hp;
        #pragma unroll
        for (int k = 0; k < 8; ++k) {
            int idx = tid + 256 * k;          // float4 index in [0,2048)
            float4 v = h4[idx];
            int row = idx >> 4;               // 16 float4 per 64-float row
            int f   = (idx & 15) << 2;
            union { _Float16 h[4]; uint2 u; } cv;
            cv.h[0] = (_Float16)v.x; cv.h[1] = (_Float16)v.y;
            cv.h[2] = (_Float16)v.z; cv.h[3] = (_Float16)v.w;
            int off = (row * 128 + f * 2) ^ ((row & 7) << 4);
            *(uint2*)(xb + off) = cv.u;
        }
        // W: each thread owns a 4(f) x 4(o) block, transposes in registers,
        // writes 8B (4 consecutive f, one o). Lanes of a 16-group write one
        // contiguous 128B LDS row -> conflict-free. Strided global reads are
        // L2-resident (W is 16KB, shared by all blocks).
        {
            const int f0 = (tid & 15) * 4;
            const int o0 = (tid >> 4) * 4;
            float4 r0 = *(const float4*)&Wg[(f0 + 0) * 64 + o0];
            float4 r1 = *(const float4*)&Wg[(f0 + 1) * 64 + o0];
            float4 r2 = *(const float4*)&Wg[(f0 + 2) * 64 + o0];
            float4 r3 = *(const float4*)&Wg[(f0 + 3) * 64 + o0];
            float col[4][4] = {{r0.x, r1.x, r2.x, r3.x},
                               {r0.y, r1.y, r2.y, r3.y},
                               {r0.z, r1.z, r2.z, r3.z},
                               {r0.w, r1.w, r2.w, r3.w}};
            #pragma unroll
            for (int c = 0; c < 4; ++c) {
                int o = o0 + c;
                union { _Float16 h[4]; uint2 u; } cv;
                cv.h[0] = (_Float16)col[c][0]; cv.h[1] = (_Float16)col[c][1];
                cv.h[2] = (_Float16)col[c][2]; cv.h[3] = (_Float16)col[c][3];
                int off = (o * 128 + f0 * 2) ^ ((o & 7) << 4);
                *(uint2*)(pb + off) = cv.u;
            }
        }
        if (tid < 2 * FOUT) sA[tid] = ag[tid];
    }

    // prefetch adj tile 0 early (latency hides under staging + phase A/B)
    int4 areg[4];
    {
        const int4* ap = (const int4*)(adjp + pi * D_ + pjb);
        #pragma unroll
        for (int q = 0; q < 4; ++q) areg[q] = ap[q];
    }
    __syncthreads();   // B1: staged h/W visible to all waves

    // ---------------- phase A: Wh = h @ W via MFMA 16x16x32 f16 ----------------
    f32x4 acc[2][4];
    #pragma unroll
    for (int mt = 0; mt < 2; ++mt)
        #pragma unroll
        for (int nt = 0; nt < 4; ++nt) acc[mt][nt] = (f32x4){0.f, 0.f, 0.f, 0.f};

    #pragma unroll
    for (int kt = 0; kt < 2; ++kt) {
        f16x8 af[2], bf[4];
        #pragma unroll
        for (int mt = 0; mt < 2; ++mt) {
            int row = w * 32 + mt * 16 + m16;
            af[mt] = *(const f16x8*)(xb + ((row * 128 + kt * 64 + g * 16) ^ ((row & 7) << 4)));
        }
        #pragma unroll
        for (int nt = 0; nt < 4; ++nt) {
            int o = nt * 16 + m16;
            bf[nt] = *(const f16x8*)(pb + ((o * 128 + kt * 64 + g * 16) ^ ((o & 7) << 4)));
        }
        #pragma unroll
        for (int mt = 0; mt < 2; ++mt)
            #pragma unroll
            for (int nt = 0; nt < 4; ++nt)
                acc[mt][nt] = __builtin_amdgcn_mfma_f32_16x16x32_f16(af[mt], bf[nt], acc[mt][nt], 0, 0, 0);
    }
    __syncthreads();   // B2: all cross-wave sX/sPt reads done before WhT overwrites sX

    // ---------------- phase B: e_i/e_j via register butterfly; WhT -> sX ----------------
    {
        float a1v[4], a2v[4];
        #pragma unroll
        for (int nt = 0; nt < 4; ++nt) {
            a1v[nt] = sA[nt * 16 + m16];
            a2v[nt] = sA[FOUT + nt * 16 + m16];
        }
        float wmax = -3.0e38f;
        #pragma unroll
        for (int mt = 0; mt < 2; ++mt) {
            #pragma unroll
            for (int r = 0; r < 4; ++r) {
                float ei = 0.f, ej = 0.f;
                #pragma unroll
                for (int nt = 0; nt < 4; ++nt) {
                    float v = acc[mt][nt][r];
                    ei += v * a1v[nt];
                    ej += v * a2v[nt];
                }
                #pragma unroll
                for (int s = 1; s < 16; s <<= 1) {
                    ei += __shfl_xor(ei, s);
                    ej += __shfl_xor(ej, s);
                }
                int row = w * 32 + mt * 16 + g * 4 + r;   // D-frag row (col=lane&15, row=(lane>>4)*4+reg)
                if (m16 == 0) { sEi[row] = ei; sEj[row] = ej; }
                wmax = fmaxf(wmax, ej);
            }
        }
        wmax = fmaxf(wmax, __shfl_xor(wmax, 16));
        wmax = fmaxf(wmax, __shfl_xor(wmax, 32));
        if (lane == 0) sMxW[w] = wmax;

        // write Wh^T f16 into sX: WhT[o][j], 4 consecutive j per (mt,nt) = one 8B write
        #pragma unroll
        for (int mt = 0; mt < 2; ++mt) {
            int j0r = w * 32 + mt * 16 + g * 4;
            #pragma unroll
            for (int nt = 0; nt < 4; ++nt) {
                int o = nt * 16 + m16;
                union { _Float16 h[4]; uint2 u; } cv;
                cv.h[0] = (_Float16)acc[mt][nt][0];
                cv.h[1] = (_Float16)acc[mt][nt][1];
                cv.h[2] = (_Float16)acc[mt][nt][2];
                cv.h[3] = (_Float16)acc[mt][nt][3];
                int off = (o * 256 + j0r * 2) ^ ((o & 7) << 4);
                *(uint2*)(xb + off) = cv.u;
            }
        }
    }
    __syncthreads();   // B3: sEj / sMxW / WhT visible to all waves. Last block barrier.

    // ---------------- phase C: P build (f16, max-shifted) + P @ Wh via MFMA ----------------
    // NO barriers in this loop: P-tile rows, sEi, sL are wave-private; sEj/WhT are
    // read-only after B3. Same-wave LDS write->read is ordered by the DS pipe.
    #pragma unroll
    for (int mt = 0; mt < 2; ++mt)
        #pragma unroll
        for (int nt = 0; nt < 4; ++nt) acc[mt][nt] = (f32x4){0.f, 0.f, 0.f, 0.f};

    const float ei_pi = sEi[pi];
    const float mxj = fmaxf(fmaxf(sMxW[0], sMxW[1]), fmaxf(sMxW[2], sMxW[3]));
    float mt_ = ei_pi + mxj;
    const float mi = mt_ > 0.f ? mt_ : ALPHA * mt_;   // = max_j leaky(ei+ej) >= any row entry
    float lpt = 0.f;

    #pragma unroll
    for (int jt = 0; jt < 4; ++jt) {
        const int j0 = jt * 32;
        // build this thread's 16 p values (row pi, j = j0+pjb .. +16)
        union { _Float16 h[8]; uint4 u; } ph0, ph1;
        #pragma unroll
        for (int q = 0; q < 4; ++q) {
            int4 av = areg[q];
            int aa[4] = {av.x, av.y, av.z, av.w};
            float4 ej4 = *(const float4*)&sEj[j0 + pjb + q * 4];
            float ejv[4] = {ej4.x, ej4.y, ej4.z, ej4.w};
            #pragma unroll
            for (int kk = 0; kk < 4; ++kk) {
                float e = ei_pi + ejv[kk];
                e = e > 0.f ? e : ALPHA * e;
                float p = (aa[kk] > 0) ? __expf(e - mi) : 0.f;   // in (0,1] -> exact f16 range
                lpt += p;
                _Float16 pv = (_Float16)p;
                if (q < 2) ph0.h[q * 4 + kk] = pv;
                else       ph1.h[(q - 2) * 4 + kk] = pv;
            }
        }
        {
            int base = pi * 64 + pjb * 2;
            *(uint4*)(pb + ((base)      ^ ((pi & 3) << 4))) = ph0.u;
            *(uint4*)(pb + ((base + 16) ^ ((pi & 3) << 4))) = ph1.u;
        }
        if (jt < 3) {
            // prefetch next adj tile (overlaps with this tile's MFMA, no barrier in between)
            const int4* ap = (const int4*)(adjp + pi * D_ + (jt + 1) * 32 + pjb);
            #pragma unroll
            for (int q = 0; q < 4; ++q) areg[q] = ap[q];
        }

        // MFMA: acc += P[:, j0:j0+32] @ Wh[j0:j0+32, :]  (P rows are this wave's own)
        f16x8 pa[2], wb[4];
        #pragma unroll
        for (int mtx = 0; mtx < 2; ++mtx) {
            int i = w * 32 + mtx * 16 + m16;
            pa[mtx] = *(const f16x8*)(pb + ((i * 64 + g * 16) ^ ((i & 3) << 4)));
        }
        #pragma unroll
        for (int nt = 0; nt < 4; ++nt) {
            int o = nt * 16 + m16;
            wb[nt] = *(const f16x8*)(xb + ((o * 256 + j0 * 2 + g * 16) ^ ((o & 7) << 4)));
        }
        #pragma unroll
        for (int mtx = 0; mtx < 2; ++mtx)
            #pragma unroll
            for (int nt = 0; nt < 4; ++nt)
                acc[mtx][nt] = __builtin_amdgcn_mfma_f32_16x16x32_f16(pa[mtx], wb[nt], acc[mtx][nt], 0, 0, 0);
    }

    // row sums -> sL (wave-private, same-wave read below)
    lpt += __shfl_xor(lpt, 1);
    if ((tid & 1) == 0) sL[pi] = lpt;

    // ---------------- epilogue: divide by row sum, write out ----------------
    #pragma unroll
    for (int mtx = 0; mtx < 2; ++mtx) {
        #pragma unroll
        for (int r = 0; r < 4; ++r) {
            int row = w * 32 + mtx * 16 + g * 4 + r;
            float inv = 1.0f / sL[row];
            #pragma unroll
            for (int nt = 0; nt < 4; ++nt)
                outp[row * 64 + nt * 16 + m16] = acc[mtx][nt][r] * inv;
        }
    }
}

extern "C" void kernel_launch(void* const* d_in, const int* in_sizes, int n_in,
                              void* d_out, int out_size, void* d_ws, size_t ws_size,
                              hipStream_t stream) {
    const float* h   = (const float*)d_in[0];
    const int*   adj = (const int*)d_in[1];
    const float* W   = (const float*)d_in[2];
    const float* a   = (const float*)d_in[3];
    float*       out = (float*)d_out;
    gat_kernel<<<dim3(16 * 256), dim3(256), 0, stream>>>(h, adj, W, a, out);
}